// Round 1
// baseline (867.133 us; speedup 1.0000x reference)
//
#include <hip/hip_runtime.h>
#include <hip/hip_bf16.h>

// Problem: relu(quant8(x) @ quant8(W)^T + bias)
//   x: [2,2048,4096] f32  -> M=4096, K=4096
//   W: [16384,4096]  f32  -> N=16384 (row-major in K, i.e. B^T layout)
//   out: [2,2048,16384] f32
// Strategy: quantize both operands to int8 (exact integer levels), then
// int8 MFMA GEMM (m97-proven 128x128 tile structure, BK=128 bytes),
// epilogue fuses (acc * sx*sw) + bias, relu.

#define HIDDEN 4096
#define INTER 16384
#define MDIM 4096

typedef int v4i __attribute__((ext_vector_type(4)));

// ---------------------------------------------------------------------------
// Quantize: q = round_ne(clamp(x, -c, c) * 127/c), packed 4 int8 per int32.
// ---------------------------------------------------------------------------
__global__ __launch_bounds__(256) void quantize_kernel(
    const float* __restrict__ x,
    signed char* __restrict__ q,
    const float* __restrict__ clip_ptr,
    int n4)
{
    int i = blockIdx.x * blockDim.x + threadIdx.x;
    if (i >= n4) return;
    float c = fabsf(clip_ptr[0]);
    float inv_scale = 127.0f / c;
    float4 v = reinterpret_cast<const float4*>(x)[i];
    int q0 = __float2int_rn(fminf(fmaxf(v.x, -c), c) * inv_scale);
    int q1 = __float2int_rn(fminf(fmaxf(v.y, -c), c) * inv_scale);
    int q2 = __float2int_rn(fminf(fmaxf(v.z, -c), c) * inv_scale);
    int q3 = __float2int_rn(fminf(fmaxf(v.w, -c), c) * inv_scale);
    int pack = (q0 & 0xff) | ((q1 & 0xff) << 8) | ((q2 & 0xff) << 16) | (q3 << 24);
    reinterpret_cast<int*>(q)[i] = pack;
}

// ---------------------------------------------------------------------------
// i8 GEMM: C[m,n] = sum_k qA[m,k] * qB[n,k]   (both row-major in K)
// 128x128 tile per block, 256 threads = 4 waves, each wave a 64x64 subtile
// (4x4 grid of 16x16x64 MFMAs). BK = 128 bytes per K-step.
// ---------------------------------------------------------------------------
__global__ __launch_bounds__(256) void gemm_i8_kernel(
    const signed char* __restrict__ qA,   // [MDIM, HIDDEN]
    const signed char* __restrict__ qB,   // [INTER, HIDDEN]
    const float* __restrict__ bias,       // [INTER]
    const float* __restrict__ wclip,
    const float* __restrict__ iclip,
    float* __restrict__ out)              // [MDIM, INTER]
{
    __shared__ __align__(16) signed char As[128 * 128];
    __shared__ __align__(16) signed char Bs[128 * 128];

    const int t = threadIdx.x;
    const int W = t >> 6;          // wave id 0..3
    const int L = t & 63;          // lane

    const int mBase = blockIdx.y * 128;
    const int nBase = blockIdx.x * 128;

    const int waveM = (W >> 1) * 64;   // wave's subtile row offset
    const int waveN = (W & 1) * 64;    // wave's subtile col offset

    v4i acc[4][4];
#pragma unroll
    for (int i = 0; i < 4; i++)
#pragma unroll
        for (int j = 0; j < 4; j++)
            acc[i][j] = (v4i){0, 0, 0, 0};

    // Staging geometry: per issue, 256 threads x 16 B = 4 KiB; a full
    // 128x128 B tile = 4 issues. Wave-uniform LDS base + lane*16 layout:
    //   lds offset = issue*4096 + W*1024 + L*16
    //   -> row = issue*32 + W*8 + (L>>3), colByte = (L&7)*16  (128 B rows)
    const int sRow = W * 8 + (L >> 3);
    const int sCol = (L & 7) * 16;
    const signed char* gA = qA + (size_t)(mBase + sRow) * HIDDEN + sCol;
    const signed char* gB = qB + (size_t)(nBase + sRow) * HIDDEN + sCol;
    const int ldsOff = W * 1024 + L * 16;

    const int lane16 = L & 15;
    const int quad = L >> 4;

    for (int k0 = 0; k0 < HIDDEN; k0 += 128) {
        __syncthreads();   // protect LDS from previous iteration's readers
#pragma unroll
        for (int i = 0; i < 4; i++) {
            __builtin_amdgcn_global_load_lds(
                (const __attribute__((address_space(1))) void*)(gA + (size_t)i * 32 * HIDDEN + k0),
                (__attribute__((address_space(3))) void*)(As + ldsOff + i * 4096),
                16, 0, 0);
            __builtin_amdgcn_global_load_lds(
                (const __attribute__((address_space(1))) void*)(gB + (size_t)i * 32 * HIDDEN + k0),
                (__attribute__((address_space(3))) void*)(Bs + ldsOff + i * 4096),
                16, 0, 0);
        }
        __syncthreads();   // compiler emits vmcnt(0) drain before barrier

#pragma unroll
        for (int kk = 0; kk < 2; kk++) {
            v4i a[4], b[4];
#pragma unroll
            for (int tm = 0; tm < 4; tm++)
                a[tm] = *(const v4i*)(&As[(waveM + tm * 16 + lane16) * 128 + kk * 64 + quad * 16]);
#pragma unroll
            for (int tn = 0; tn < 4; tn++)
                b[tn] = *(const v4i*)(&Bs[(waveN + tn * 16 + lane16) * 128 + kk * 64 + quad * 16]);
#pragma unroll
            for (int tm = 0; tm < 4; tm++)
#pragma unroll
                for (int tn = 0; tn < 4; tn++)
                    acc[tm][tn] = __builtin_amdgcn_mfma_i32_16x16x64_i8(
                        a[tm], b[tn], acc[tm][tn], 0, 0, 0);
        }
    }

    // Epilogue: out = relu(acc * (|wc|/127)*(|ic|/127) + bias)
    const float scale = (fabsf(wclip[0]) / 127.0f) * (fabsf(iclip[0]) / 127.0f);

    float bv[4];
#pragma unroll
    for (int tn = 0; tn < 4; tn++)
        bv[tn] = bias[nBase + waveN + tn * 16 + lane16];

    // C/D mapping (guide-verified, dtype-independent): col = lane&15,
    // row = quad*4 + reg.
#pragma unroll
    for (int tm = 0; tm < 4; tm++) {
#pragma unroll
        for (int r = 0; r < 4; r++) {
            int m = mBase + waveM + tm * 16 + quad * 4 + r;
            float* orow = out + (size_t)m * INTER + nBase + waveN + lane16;
#pragma unroll
            for (int tn = 0; tn < 4; tn++) {
                float v = (float)acc[tm][tn][r] * scale + bv[tn];
                orow[tn * 16] = fmaxf(v, 0.0f);
            }
        }
    }
}

extern "C" void kernel_launch(void* const* d_in, const int* in_sizes, int n_in,
                              void* d_out, int out_size, void* d_ws, size_t ws_size,
                              hipStream_t stream) {
    const float* hidden_states  = (const float*)d_in[0];  // [2,2048,4096]
    const float* weight         = (const float*)d_in[1];  // [16384,4096]
    const float* bias           = (const float*)d_in[2];  // [16384]
    const float* weight_clip    = (const float*)d_in[3];  // scalar
    const float* input_clip     = (const float*)d_in[4];  // scalar
    float* out = (float*)d_out;

    signed char* qA = (signed char*)d_ws;                         // 16 MiB
    signed char* qB = qA + (size_t)MDIM * HIDDEN;                 // 64 MiB

    // Quantize activations: 4096*4096 / 4 elems per thread
    {
        int n4 = MDIM * HIDDEN / 4;
        quantize_kernel<<<n4 / 256, 256, 0, stream>>>(hidden_states, qA, input_clip, n4);
    }
    // Quantize weights: 16384*4096 / 4
    {
        int n4 = INTER * HIDDEN / 4;
        quantize_kernel<<<n4 / 256, 256, 0, stream>>>(weight, qB, weight_clip, n4);
    }

    dim3 grid(INTER / 128, MDIM / 128);   // 128 x 32 = 4096 blocks
    gemm_i8_kernel<<<grid, 256, 0, stream>>>(qA, qB, bias, weight_clip, input_clip, out);
}

// Round 2
// 816.527 us; speedup vs baseline: 1.0620x; 1.0620x over previous
//
#include <hip/hip_runtime.h>
#include <hip/hip_bf16.h>

// Problem: relu(quant8(x) @ quant8(W)^T + bias)
//   x: [2,2048,4096] f32  -> M=4096, K=4096
//   W: [16384,4096]  f32  -> N=16384 (row-major in K, i.e. B^T layout)
//   out: [2,2048,16384] f32
// Strategy: quantize both operands to int8 (exact integer levels), then
// int8 MFMA GEMM (m97-proven 128x128 tile structure, BK=128 bytes),
// epilogue fuses (acc * sx*sw) + bias, relu.
//
// R1 change: XOR-swizzled LDS layout. R0 had SQ_LDS_BANK_CONFLICT=1.0e8
// (~36% of cycles): fragment ds_read_b128 put all 16 lanes of a quad on the
// same 4 banks (row*128 ≡ 0 mod bank stride). Physical chunk = logical ^
// (row&7) spreads the 16 lanes across all 8 bank-groups (2/group = free).
// Staging implements the swizzle by permuting the per-lane SOURCE column
// (global_load_lds LDS destination must stay base+lane*16).

#define HIDDEN 4096
#define INTER 16384
#define MDIM 4096

typedef int v4i __attribute__((ext_vector_type(4)));

// ---------------------------------------------------------------------------
// Quantize: q = round_ne(clamp(x, -c, c) * 127/c), packed 4 int8 per int32.
// ---------------------------------------------------------------------------
__global__ __launch_bounds__(256) void quantize_kernel(
    const float* __restrict__ x,
    signed char* __restrict__ q,
    const float* __restrict__ clip_ptr,
    int n4)
{
    int i = blockIdx.x * blockDim.x + threadIdx.x;
    if (i >= n4) return;
    float c = fabsf(clip_ptr[0]);
    float inv_scale = 127.0f / c;
    float4 v = reinterpret_cast<const float4*>(x)[i];
    int q0 = __float2int_rn(fminf(fmaxf(v.x, -c), c) * inv_scale);
    int q1 = __float2int_rn(fminf(fmaxf(v.y, -c), c) * inv_scale);
    int q2 = __float2int_rn(fminf(fmaxf(v.z, -c), c) * inv_scale);
    int q3 = __float2int_rn(fminf(fmaxf(v.w, -c), c) * inv_scale);
    int pack = (q0 & 0xff) | ((q1 & 0xff) << 8) | ((q2 & 0xff) << 16) | (q3 << 24);
    reinterpret_cast<int*>(q)[i] = pack;
}

// ---------------------------------------------------------------------------
// i8 GEMM: C[m,n] = sum_k qA[m,k] * qB[n,k]   (both row-major in K)
// 128x128 tile per block, 256 threads = 4 waves, each wave a 64x64 subtile
// (4x4 grid of 16x16x64 MFMAs). BK = 128 bytes per K-step.
// ---------------------------------------------------------------------------
__global__ __launch_bounds__(256) void gemm_i8_kernel(
    const signed char* __restrict__ qA,   // [MDIM, HIDDEN]
    const signed char* __restrict__ qB,   // [INTER, HIDDEN]
    const float* __restrict__ bias,       // [INTER]
    const float* __restrict__ wclip,
    const float* __restrict__ iclip,
    float* __restrict__ out)              // [MDIM, INTER]
{
    __shared__ __align__(16) signed char As[128 * 128];
    __shared__ __align__(16) signed char Bs[128 * 128];

    const int t = threadIdx.x;
    const int W = t >> 6;          // wave id 0..3
    const int L = t & 63;          // lane

    const int mBase = blockIdx.y * 128;
    const int nBase = blockIdx.x * 128;

    const int waveM = (W >> 1) * 64;   // wave's subtile row offset
    const int waveN = (W & 1) * 64;    // wave's subtile col offset

    v4i acc[4][4];
#pragma unroll
    for (int i = 0; i < 4; i++)
#pragma unroll
        for (int j = 0; j < 4; j++)
            acc[i][j] = (v4i){0, 0, 0, 0};

    // Staging geometry: per issue, 256 threads x 16 B = 4 KiB; a full
    // 128x128 B tile = 4 issues. LDS dest is fixed: issue*4096 + W*1024 + L*16
    //   -> physical (row = issue*32 + W*8 + (L>>3), chunk = L&7)
    // Swizzle: physical chunk ch holds logical chunk ch ^ (row&7), so the
    // per-lane SOURCE column is ((L&7) ^ ((L>>3)&7)) * 16  (row&7 == (L>>3)&7
    // since issue*32 and W*8 are multiples of 8). Still within the same
    // 128-B segment -> coalescing preserved.
    const int sRow = W * 8 + (L >> 3);
    const int sCol = ((L & 7) ^ ((L >> 3) & 7)) * 16;
    const signed char* gA = qA + (size_t)(mBase + sRow) * HIDDEN + sCol;
    const signed char* gB = qB + (size_t)(nBase + sRow) * HIDDEN + sCol;
    const int ldsOff = W * 1024 + L * 16;

    const int lane16 = L & 15;
    const int quad = L >> 4;
    const int swz = (lane16 & 7);     // row&7 for all fragment rows

    for (int k0 = 0; k0 < HIDDEN; k0 += 128) {
        __syncthreads();   // protect LDS from previous iteration's readers
#pragma unroll
        for (int i = 0; i < 4; i++) {
            __builtin_amdgcn_global_load_lds(
                (const __attribute__((address_space(1))) void*)(gA + (size_t)i * 32 * HIDDEN + k0),
                (__attribute__((address_space(3))) void*)(As + ldsOff + i * 4096),
                16, 0, 0);
            __builtin_amdgcn_global_load_lds(
                (const __attribute__((address_space(1))) void*)(gB + (size_t)i * 32 * HIDDEN + k0),
                (__attribute__((address_space(3))) void*)(Bs + ldsOff + i * 4096),
                16, 0, 0);
        }
        __syncthreads();   // compiler emits vmcnt(0) drain before barrier

#pragma unroll
        for (int kk = 0; kk < 2; kk++) {
            v4i a[4], b[4];
#pragma unroll
            for (int tm = 0; tm < 4; tm++)
                a[tm] = *(const v4i*)(&As[(waveM + tm * 16 + lane16) * 128
                                          + (((kk * 4 + quad) ^ swz) * 16)]);
#pragma unroll
            for (int tn = 0; tn < 4; tn++)
                b[tn] = *(const v4i*)(&Bs[(waveN + tn * 16 + lane16) * 128
                                          + (((kk * 4 + quad) ^ swz) * 16)]);
#pragma unroll
            for (int tm = 0; tm < 4; tm++)
#pragma unroll
                for (int tn = 0; tn < 4; tn++)
                    acc[tm][tn] = __builtin_amdgcn_mfma_i32_16x16x64_i8(
                        a[tm], b[tn], acc[tm][tn], 0, 0, 0);
        }
    }

    // Epilogue: out = relu(acc * (|wc|/127)*(|ic|/127) + bias)
    const float scale = (fabsf(wclip[0]) / 127.0f) * (fabsf(iclip[0]) / 127.0f);

    float bv[4];
#pragma unroll
    for (int tn = 0; tn < 4; tn++)
        bv[tn] = bias[nBase + waveN + tn * 16 + lane16];

    // C/D mapping (guide-verified, dtype-independent): col = lane&15,
    // row = quad*4 + reg.
#pragma unroll
    for (int tm = 0; tm < 4; tm++) {
#pragma unroll
        for (int r = 0; r < 4; r++) {
            int m = mBase + waveM + tm * 16 + quad * 4 + r;
            float* orow = out + (size_t)m * INTER + nBase + waveN + lane16;
#pragma unroll
            for (int tn = 0; tn < 4; tn++) {
                float v = (float)acc[tm][tn][r] * scale + bv[tn];
                orow[tn * 16] = fmaxf(v, 0.0f);
            }
        }
    }
}

extern "C" void kernel_launch(void* const* d_in, const int* in_sizes, int n_in,
                              void* d_out, int out_size, void* d_ws, size_t ws_size,
                              hipStream_t stream) {
    const float* hidden_states  = (const float*)d_in[0];  // [2,2048,4096]
    const float* weight         = (const float*)d_in[1];  // [16384,4096]
    const float* bias           = (const float*)d_in[2];  // [16384]
    const float* weight_clip    = (const float*)d_in[3];  // scalar
    const float* input_clip     = (const float*)d_in[4];  // scalar
    float* out = (float*)d_out;

    signed char* qA = (signed char*)d_ws;                         // 16 MiB
    signed char* qB = qA + (size_t)MDIM * HIDDEN;                 // 64 MiB

    // Quantize activations: 4096*4096 / 4 elems per thread
    {
        int n4 = MDIM * HIDDEN / 4;
        quantize_kernel<<<n4 / 256, 256, 0, stream>>>(hidden_states, qA, input_clip, n4);
    }
    // Quantize weights: 16384*4096 / 4
    {
        int n4 = INTER * HIDDEN / 4;
        quantize_kernel<<<n4 / 256, 256, 0, stream>>>(weight, qB, weight_clip, n4);
    }

    dim3 grid(INTER / 128, MDIM / 128);   // 128 x 32 = 4096 blocks
    gemm_i8_kernel<<<grid, 256, 0, stream>>>(qA, qB, bias, weight_clip, input_clip, out);
}